// Round 2
// baseline (1217.628 us; speedup 1.0000x reference)
//
#include <hip/hip_runtime.h>

#define N_NODES 16384
#define E_EDGES 524288
#define IN_DIM  256
#define OUT_DIM 128
#define CAP     128    // per-row bucket capacity; deg ~ Poisson(32), P(deg>128) ~ 1e-35
#define GEMM_BLOCKS (N_NODES / 32)          // 512
#define BUCKET_BLOCKS (E_EDGES / 256)       // 2048
#define ZERO_BLOCKS 4096                    // A-zeroing blocks (grid-stride nt stores)

typedef float f4_t __attribute__((ext_vector_type(4)));

// ---- K1 (merged, 3 block ranges):
//   [0, GEMM_BLOCKS)                      x = input @ W + row norms
//   [GEMM_BLOCKS, +BUCKET_BLOCKS)         bucket edge cols by row (atomics)
//   [+BUCKET_BLOCKS, +ZERO_BLOCKS)        stream zeros over dense A (nt, full
//                                         occupancy — same structure as the
//                                         6.2 TB/s harness fill kernel)
// The three halves share no data; the BW-bound zeroing overlaps the
// latency-bound bucketing and the compute-bound GEMM instead of paying for a
// low-occupancy dense write inside the row kernel (round-1's mistake).
__global__ __launch_bounds__(256) void gemm_bucket_zero(
    const float* __restrict__ inp, const float* __restrict__ W,
    float* __restrict__ x, float* __restrict__ nrm2,
    const int* __restrict__ rows, const int* __restrict__ cols,
    int* __restrict__ deg, int* __restrict__ bucket,
    float* __restrict__ A) {
    const int t = threadIdx.x;

    if (blockIdx.x >= GEMM_BLOCKS + BUCKET_BLOCKS) {
        // ---- zero half: grid-stride nt float4 stores over all of A.
        // total = ZERO_BLOCKS*256*64 float4 = N*N/4 exactly.
        const int b = blockIdx.x - (GEMM_BLOCKS + BUCKET_BLOCKS);
        f4_t* A4 = (f4_t*)A;
        const f4_t z = {0.f, 0.f, 0.f, 0.f};
        size_t idx = (size_t)b * 256 + t;
#pragma unroll
        for (int k = 0; k < 64; ++k)
            __builtin_nontemporal_store(z, A4 + idx + (size_t)k * (ZERO_BLOCKS * 256));
        return;
    }

    if (blockIdx.x >= GEMM_BLOCKS) {
        // ---- bucket half: one thread per edge
        const int e = (blockIdx.x - GEMM_BLOCKS) * 256 + t;
        const int r = rows[e];
        int k = atomicAdd(&deg[r], 1);
        if (k < CAP) bucket[(size_t)r * CAP + k] = cols[e];
        return;
    }

    // ---- GEMM half: 32 rows/block; thread (g=t>>5, c=t&31) owns a 4x4 tile.
    const int g  = t >> 5;
    const int c  = t & 31;
    const int n0 = blockIdx.x * 32;

    __shared__ float4 sA4[32 * (IN_DIM / 4)];          // 32 KB
    const float4* inp4 = (const float4*)(inp + (size_t)n0 * IN_DIM);
#pragma unroll
    for (int i = 0; i < 8; ++i) sA4[t + 256 * i] = inp4[t + 256 * i];
    __syncthreads();

    const float4* W4 = (const float4*)W;               // [IN_DIM][32]
    float4 acc[4];
#pragma unroll
    for (int i = 0; i < 4; ++i) acc[i] = make_float4(0.f, 0.f, 0.f, 0.f);

    for (int kq = 0; kq < IN_DIM / 4; ++kq) {
        float4 w0 = W4[(kq * 4 + 0) * 32 + c];
        float4 w1 = W4[(kq * 4 + 1) * 32 + c];
        float4 w2 = W4[(kq * 4 + 2) * 32 + c];
        float4 w3 = W4[(kq * 4 + 3) * 32 + c];
#pragma unroll
        for (int i = 0; i < 4; ++i) {
            float4 s = sA4[(4 * g + i) * 64 + kq];
            acc[i].x += s.x * w0.x + s.y * w1.x + s.z * w2.x + s.w * w3.x;
            acc[i].y += s.x * w0.y + s.y * w1.y + s.z * w2.y + s.w * w3.y;
            acc[i].z += s.x * w0.z + s.y * w1.z + s.z * w2.z + s.w * w3.z;
            acc[i].w += s.x * w0.w + s.y * w1.w + s.z * w2.w + s.w * w3.w;
        }
    }

    float4* x4 = (float4*)x;
#pragma unroll
    for (int i = 0; i < 4; ++i) {
        const int r = n0 + 4 * g + i;
        x4[(size_t)r * 32 + c] = acc[i];
        float p = acc[i].x * acc[i].x + acc[i].y * acc[i].y
                + acc[i].z * acc[i].z + acc[i].w * acc[i].w;
#pragma unroll
        for (int off = 16; off > 0; off >>= 1) p += __shfl_xor(p, off);
        if (c == 0) nrm2[r] = p;
    }
}

// ---- K2: per-row scores + softmax + SPARSE atomic scatter into pre-zeroed A.
// No dense traffic here at all (A was zeroed in K1's dispatch); LDS is tiny
// (sex[CAP] + 1 float) so occupancy is back to 8 blocks/CU. Only ~32 atomics
// per row (~524K total, ~67 MB of line RMW traffic ≈ 11 us of BW).
// s = (sum_d relu(x_r[d]*x_c[d]) * a[d]) * rsqrt(n2_r*n2_c)  (== ref exactly)
// ex = s>0 ? exp(s) : 0  (shift-free softmax: ref's exp(s-smax)/ssum is
// shift-invariant and exp can't overflow; s<=0 edges give exactly 0 in ref).
// ssum==0 row -> uniform 1/deg, matching ref (all s==NEG_BIG => exps == 1).
// Duplicate (r,c) edges: atomicAdd accumulates, same as ref's .at[].add.
__global__ __launch_bounds__(256) void score_scatter(
    const float* __restrict__ x, const float* __restrict__ nrm2,
    const int* __restrict__ deg, const int* __restrict__ bucket,
    const float* __restrict__ a, float* __restrict__ A) {
    const int r    = blockIdx.x;
    const int t    = threadIdx.x;
    const int hw   = t >> 5;
    const int lane = t & 31;
    int d = deg[r]; if (d > CAP) d = CAP;
    if (d == 0) return;                      // block-uniform: row stays zero

    __shared__ float sex[CAP];
    __shared__ float ssum_s;
    if (t == 0) ssum_s = 0.f;

    const float4* x4 = (const float4*)x;
    const float4* a4 = (const float4*)a;
    const int* buk = bucket + (size_t)r * CAP;
    float4 xi = x4[(size_t)r * 32 + lane];
    float4 av = a4[lane];
    const float n2r = nrm2[r];
    __syncthreads();   // publishes ssum_s = 0 before any atomicAdd to it

    float local = 0.f;
    for (int i = hw; i < d; i += 8) {
        int c = buk[i];
        float4 xj = x4[(size_t)c * 32 + lane];
        float tv = fmaxf(xi.x * xj.x, 0.f) * av.x
                 + fmaxf(xi.y * xj.y, 0.f) * av.y
                 + fmaxf(xi.z * xj.z, 0.f) * av.z
                 + fmaxf(xi.w * xj.w, 0.f) * av.w;
#pragma unroll
        for (int off = 16; off > 0; off >>= 1) tv += __shfl_xor(tv, off);
        if (lane == 0) {
            float s = tv * rsqrtf(n2r * nrm2[c]);
            float ex = (s > 0.f) ? expf(s) : 0.f;
            sex[i] = ex;
            local += ex;
        }
    }
    if (lane == 0 && local != 0.f) atomicAdd(&ssum_s, local);
    __syncthreads();   // sex + ssum visible
    const float ssum = ssum_s;

    float* Arow = A + (size_t)r * N_NODES;
    if (ssum > 0.f) {
        const float inv = 1.0f / ssum;
        for (int i = t; i < d; i += 256) {
            float ex = sex[i];
            if (ex == 0.f) continue;   // reference value is exactly 0 here
            atomicAdd(&Arow[buk[i]], ex * inv);
        }
    } else {
        const float u = 1.0f / (float)d;
        for (int i = t; i < d; i += 256)
            atomicAdd(&Arow[buk[i]], u);
    }
}

extern "C" void kernel_launch(void* const* d_in, const int* in_sizes, int n_in,
                              void* d_out, int out_size, void* d_ws, size_t ws_size,
                              hipStream_t stream) {
    const float* inp  = (const float*)d_in[0];
    const int*   edge = (const int*)d_in[1];   // [2, E]: rows then cols
    const float* W    = (const float*)d_in[2];
    const float* a    = (const float*)d_in[3];
    const int* rows = edge;
    const int* cols = edge + E_EDGES;

    float* x = (float*)d_out;                          // [N, OUT_DIM]
    float* A = x + (size_t)N_NODES * OUT_DIM;          // [N, N]

    float* nrm2   = (float*)d_ws;                      // N floats
    int*   deg    = (int*)(nrm2 + N_NODES);            // N ints
    int*   bucket = deg + N_NODES;                     // N*CAP ints (8 MB)

    hipMemsetAsync(deg, 0, N_NODES * sizeof(int), stream);
    gemm_bucket_zero<<<GEMM_BLOCKS + BUCKET_BLOCKS + ZERO_BLOCKS, 256, 0, stream>>>(
        inp, W, x, nrm2, rows, cols, deg, bucket, A);
    score_scatter<<<N_NODES, 256, 0, stream>>>(x, nrm2, deg, bucket, a, A);
}

// Round 5
// 1130.104 us; speedup vs baseline: 1.0774x; 1.0774x over previous
//
#include <hip/hip_runtime.h>

#define N_NODES 16384
#define E_EDGES 524288
#define IN_DIM  256
#define OUT_DIM 128
#define CAP     128    // per-row bucket capacity; deg ~ Poisson(32), P(deg>128) ~ 1e-44
#define GEMM_BLOCKS (N_NODES / 32)          // 512
#define BUCKET_BLOCKS (E_EDGES / 256)       // 2048

typedef float f4_t __attribute__((ext_vector_type(4)));

// ---- K1 (merged): blocks [0, GEMM_BLOCKS) do x = input @ W + row norms;
// blocks [GEMM_BLOCKS, ...) bucket edge columns by row. No dense-A work here:
// K2 emits A in a single nontemporal pass (write-once).
__global__ __launch_bounds__(256) void gemm_bucket(
    const float* __restrict__ inp, const float* __restrict__ W,
    float* __restrict__ x, float* __restrict__ nrm2,
    const int* __restrict__ rows, const int* __restrict__ cols,
    int* __restrict__ deg, int* __restrict__ bucket) {
    const int t = threadIdx.x;

    if (blockIdx.x >= GEMM_BLOCKS) {
        // ---- bucket half: one thread per edge
        const int e = (blockIdx.x - GEMM_BLOCKS) * 256 + t;
        const int r = rows[e];
        int k = atomicAdd(&deg[r], 1);
        if (k < CAP) bucket[(size_t)r * CAP + k] = cols[e];
        return;
    }

    // ---- GEMM half: 32 rows/block; thread (g=t>>5, c=t&31) owns a 4x4 tile.
    const int g  = t >> 5;
    const int c  = t & 31;
    const int n0 = blockIdx.x * 32;

    __shared__ float4 sA4[32 * (IN_DIM / 4)];          // 32 KB
    const float4* inp4 = (const float4*)(inp + (size_t)n0 * IN_DIM);
#pragma unroll
    for (int i = 0; i < 8; ++i) sA4[t + 256 * i] = inp4[t + 256 * i];
    __syncthreads();

    const float4* W4 = (const float4*)W;               // [IN_DIM][32]
    float4 acc[4];
#pragma unroll
    for (int i = 0; i < 4; ++i) acc[i] = make_float4(0.f, 0.f, 0.f, 0.f);

    for (int kq = 0; kq < IN_DIM / 4; ++kq) {
        float4 w0 = W4[(kq * 4 + 0) * 32 + c];
        float4 w1 = W4[(kq * 4 + 1) * 32 + c];
        float4 w2 = W4[(kq * 4 + 2) * 32 + c];
        float4 w3 = W4[(kq * 4 + 3) * 32 + c];
#pragma unroll
        for (int i = 0; i < 4; ++i) {
            float4 s = sA4[(4 * g + i) * 64 + kq];
            acc[i].x += s.x * w0.x + s.y * w1.x + s.z * w2.x + s.w * w3.x;
            acc[i].y += s.x * w0.y + s.y * w1.y + s.z * w2.y + s.w * w3.y;
            acc[i].z += s.x * w0.z + s.y * w1.z + s.z * w2.z + s.w * w3.z;
            acc[i].w += s.x * w0.w + s.y * w1.w + s.z * w2.w + s.w * w3.w;
        }
    }

    float4* x4 = (float4*)x;
#pragma unroll
    for (int i = 0; i < 4; ++i) {
        const int r = n0 + 4 * g + i;
        x4[(size_t)r * 32 + c] = acc[i];
        float p = acc[i].x * acc[i].x + acc[i].y * acc[i].y
                + acc[i].z * acc[i].z + acc[i].w * acc[i].w;
#pragma unroll
        for (int off = 16; off > 0; off >>= 1) p += __shfl_xor(p, off);
        if (c == 0) nrm2[r] = p;
    }
}

// ---- K2: scores + softmax + SINGLE-PASS dense row emit (write-once A).
// A row has <= ~70 nonzeros of 16384. LDS keeps {col, ex} lists + a 2 KB
// column bitmap (~3 KB total -> full occupancy). Emit streams the row as
// nontemporal float4 stores; a 4-bit nibble lookup says "all-zero chunk"
// (~99% of chunks -> pure store); nonzero chunks linear-scan the <=d edge
// list, accumulating duplicate (r,c) edges exactly like ref's .at[].add.
// ROUND-4 BUG FIX: one row = 16384 floats = 4096 float4 chunks = 256 threads
// x 16 iterations. Rounds 3/4 iterated k<64 (4 rows' worth) -> OOB stores
// past the output buffer -> illegal address abort. Now k<16; bm[idx>>3]
// tops out at 511 (bitmap has 512 words) -- both OOBs gone.
// Math (identical to passing rounds 0-2):
//   s  = (sum_d relu(x_r[d]*x_c[d]) * a[d]) * rsqrt(n2_r * n2_c)
//   ex = s>0 ? exp(s) : 0   (shift-free softmax, == ref exactly; s<=0 edges
//        are exactly 0 in ref too)
//   ssum==0 row -> uniform 1/deg per edge occurrence (ref: all NEG_BIG)
__global__ __launch_bounds__(256) void score_emit(
    const float* __restrict__ x, const float* __restrict__ nrm2,
    const int* __restrict__ deg, const int* __restrict__ bucket,
    const float* __restrict__ a, float* __restrict__ A) {
    const int r    = blockIdx.x;
    const int t    = threadIdx.x;
    const int hw   = t >> 5;
    const int lane = t & 31;
    int d = deg[r]; if (d > CAP) d = CAP;

    __shared__ int      scol[CAP];          // 512 B
    __shared__ float    sval[CAP];          // 512 B (unnormalized ex)
    __shared__ unsigned bm[N_NODES / 32];   // 2 KB column bitmap (512 words)
    __shared__ float    ssum_s;

    if (t == 0) ssum_s = 0.f;
    bm[t] = 0u;
    bm[t + 256] = 0u;

    const float4* x4 = (const float4*)x;
    const float4* a4 = (const float4*)a;
    const int* buk = bucket + (size_t)r * CAP;
    float4 xi = x4[(size_t)r * 32 + lane];
    float4 av = a4[lane];
    const float n2r = nrm2[r];
    __syncthreads();   // bitmap + ssum init visible before phase-1 updates

    // ---- phase 1: gather, score, record {col, ex}, set bitmap bits
    float local = 0.f;
    for (int i = hw; i < d; i += 8) {
        int c = buk[i];
        float4 xj = x4[(size_t)c * 32 + lane];
        float tv = fmaxf(xi.x * xj.x, 0.f) * av.x
                 + fmaxf(xi.y * xj.y, 0.f) * av.y
                 + fmaxf(xi.z * xj.z, 0.f) * av.z
                 + fmaxf(xi.w * xj.w, 0.f) * av.w;
#pragma unroll
        for (int off = 16; off > 0; off >>= 1) tv += __shfl_xor(tv, off);
        if (lane == 0) {
            float s = tv * rsqrtf(n2r * nrm2[c]);
            float ex = (s > 0.f) ? expf(s) : 0.f;
            scol[i] = c;
            sval[i] = ex;
            local += ex;
            // mark column even when ex==0 (chunk rebuild yields exact 0.0)
            atomicOr(&bm[c >> 5], 1u << (c & 31));
        }
    }
    if (lane == 0 && local != 0.f) atomicAdd(&ssum_s, local);
    __syncthreads();   // scol/sval/bm/ssum all published

    const float ssum  = ssum_s;
    const bool  unif  = (ssum <= 0.f);
    const float scale = unif ? ((d > 0) ? 1.0f / (float)d : 0.f)
                             : 1.0f / ssum;

    // ---- phase 2: stream the dense row once, nontemporal.
    // 4096 float4 chunks / 256 threads = 16 iterations. (k<16, NOT 64!)
    f4_t* dst = (f4_t*)(A + (size_t)r * N_NODES);
    for (int k = 0; k < 16; ++k) {
        const int idx = t + 256 * k;                    // float4 index in row
        unsigned nib = (bm[idx >> 3] >> ((idx & 7) << 2)) & 0xFu;
        float v0 = 0.f, v1 = 0.f, v2 = 0.f, v3 = 0.f;
        if (nib) {
            const int cbase = idx << 2;
            for (int i = 0; i < d; ++i) {
                int c = scol[i] - cbase;                // match this chunk?
                if ((unsigned)c < 4u) {
                    float val = unif ? scale : sval[i] * scale;
                    v0 += (c == 0) ? val : 0.f;
                    v1 += (c == 1) ? val : 0.f;
                    v2 += (c == 2) ? val : 0.f;
                    v3 += (c == 3) ? val : 0.f;
                }
            }
        }
        f4_t v = {v0, v1, v2, v3};
        __builtin_nontemporal_store(v, dst + idx);
    }
}

extern "C" void kernel_launch(void* const* d_in, const int* in_sizes, int n_in,
                              void* d_out, int out_size, void* d_ws, size_t ws_size,
                              hipStream_t stream) {
    const float* inp  = (const float*)d_in[0];
    const int*   edge = (const int*)d_in[1];   // [2, E]: rows then cols
    const float* W    = (const float*)d_in[2];
    const float* a    = (const float*)d_in[3];
    const int* rows = edge;
    const int* cols = edge + E_EDGES;

    float* x = (float*)d_out;                          // [N, OUT_DIM]
    float* A = x + (size_t)N_NODES * OUT_DIM;          // [N, N]

    float* nrm2   = (float*)d_ws;                      // N floats
    int*   deg    = (int*)(nrm2 + N_NODES);            // N ints
    int*   bucket = deg + N_NODES;                     // N*CAP ints (8 MB)

    hipMemsetAsync(deg, 0, N_NODES * sizeof(int), stream);
    gemm_bucket<<<GEMM_BLOCKS + BUCKET_BLOCKS, 256, 0, stream>>>(
        inp, W, x, nrm2, rows, cols, deg, bucket);
    score_emit<<<N_NODES, 256, 0, stream>>>(x, nrm2, deg, bucket, a, A);
}